// Round 13
// baseline (114.926 us; speedup 1.0000x reference)
//
#include <hip/hip_runtime.h>

typedef unsigned int u32;
typedef unsigned short u16;
typedef __bf16 bf16x8 __attribute__((ext_vector_type(8)));
typedef float f32x4 __attribute__((ext_vector_type(4)));

static __device__ __forceinline__ u16 f2bf(float f) {
  u32 u = __float_as_uint(f);
  return (u16)((u + 0x7fffu + ((u >> 16) & 1u)) >> 16);  // RTNE
}
static __device__ __forceinline__ u32 pk2(u16 lo, u16 hi) {
  return (u32)lo | ((u32)hi << 16);
}

// ---- prep: zero out; L2-normalize shapelets over s; emit bf16 in FRAGMENT order ----
// chunk = c*8 + (k>>4)*2 + (s>>5) (512 u16); lane L=(m+16h) holds elems [L*8,L*8+8)
// = shn[k=(k>>4)*16+m][s=(s>>5)*32+8h .. +7].
__global__ __launch_bounds__(256) void prep_kernel(const float* __restrict__ sh,
                                                   u16* __restrict__ shn2,
                                                   float* __restrict__ out) {
  if (blockIdx.x == 0) {  // zero the 32*64 output (atomicMax target)
    float4 z = {0.f, 0.f, 0.f, 0.f};
    *(float4*)&out[threadIdx.x * 8] = z;
    *(float4*)&out[threadIdx.x * 8 + 4] = z;
  }
  const int s = threadIdx.x & 63;
  const int wv = threadIdx.x >> 6;
  const int row0 = blockIdx.x * 16 + wv * 4;
#pragma unroll
  for (int r = 0; r < 4; ++r) {
    const int row = row0 + r;  // = c*64 + k
    float v = sh[row * 64 + s];
    float ss = v * v;
#pragma unroll
    for (int o = 1; o < 64; o <<= 1) ss += __shfl_xor(ss, o, 64);
    float iw = 1.0f / fmaxf(sqrtf(ss), 1e-8f);
    const int c = row >> 6, k = row & 63;
    const int chunk = c * 8 + (k >> 4) * 2 + (s >> 5);
    const int pos = ((k & 15) + (((s & 31) >> 3) << 4)) * 8 + (s & 7);
    shn2[chunk * 512 + pos] = f2bf(v * iw);
  }
}

#define WT 256
#define CSTRIDE 168   // u32 per (copy, channel): 160 data + 8 pad (≡8 mod 32)
#define SSTRIDE 2728  // u32 per shift-copy: 16*168 + 40 pad (≡8 mod 32)
#define IWS 264       // f32 stride of invwb rows (256 + 8 pad)

// grid (16, 32): blockIdx.x = w-tile (256 w's), blockIdx.y = b.
// 8 waves = 4 w-groups x 2 c-groups; wave tile = 64 w x 64 k x 8 channels.
// Per c-iteration: 12 LDS b64 (af) + 4 LDS b128 (iw) + 8 global (B) feed 32 MFMA.
// Cross-cgrp partial-sum reduction via LDS before the relu/max epilogue.
__global__ __launch_bounds__(512, 2) void main_kernel(const float* __restrict__ x,
                                                      const u16* __restrict__ shn2,
                                                      float* __restrict__ out) {
  __shared__ u32 xs[4 * SSTRIDE];    // 43648 B: bf16 x-slice, 4 shifted pair-packed copies
  __shared__ float invwb[16 * IWS];  // 16896 B: fp32 inv-window-norms (pre-multiplied 1/C)
  __shared__ float red2[4][4][64][4];  // 16384 B: cross-cgrp reduction (one mt-slice)
  __shared__ int redbuf[64];         // per-block max reduction
  // total 77184 B -> 2 blocks/CU

  const int tid = threadIdx.x;
  const int lane = tid & 63;
  const int wid = tid >> 6;
  const int w0 = blockIdx.x * WT;
  const int b = blockIdx.y;
  const float* xb = x + (size_t)b * 16 * 4096;

  if (tid < 64) redbuf[tid] = 0;

  // ---- phase A1: stage x-slice as bf16; copy s holds pairs (2j+s, 2j+s+1) ----
  {
    const int q = tid & 31;  // chunk: elems [16q, 16q+20)
    const int c = tid >> 5;
    if (q < 20) {
      const float* xc = xb + c * 4096;
      const int e0 = w0 + 16 * q;
      float xv[20];
      if (e0 + 19 < 4096) {
#pragma unroll
        for (int r = 0; r < 5; ++r) *(float4*)&xv[4 * r] = *(const float4*)&xc[e0 + 4 * r];
      } else {
#pragma unroll
        for (int j = 0; j < 20; ++j) {
          int g = e0 + j;
          xv[j] = xc[g < 4096 ? g : 4095];
        }
      }
      u16 bf[20];
#pragma unroll
      for (int j = 0; j < 20; ++j) bf[j] = f2bf(xv[j]);
#pragma unroll
      for (int s = 0; s < 4; ++s) {
        u32 pk[8];
#pragma unroll
        for (int r = 0; r < 8; ++r) pk[r] = pk2(bf[2 * r + s], bf[2 * r + s + 1]);
        u32* dst = &xs[s * SSTRIDE + c * CSTRIDE + 8 * q];
        *(uint4*)dst = make_uint4(pk[0], pk[1], pk[2], pk[3]);
        *(uint4*)(dst + 4) = make_uint4(pk[4], pk[5], pk[6], pk[7]);
      }
    }
  }

  // ---- phase A2: window inverse norms, streaming, fp32 out ----
  {
    const int c = tid >> 5;
    const int wb = (tid & 31) * 8;
    const float* xc = xb + c * 4096;
    const int e0 = w0 + wb;
    float hd[8], tl[8], ss = 0.f;
    if (e0 + 71 < 4096) {
#pragma unroll
      for (int r = 0; r < 16; ++r) {
        float4 v = *(const float4*)&xc[e0 + 4 * r];
        if (r < 2) {
          hd[4 * r + 0] = v.x; hd[4 * r + 1] = v.y;
          hd[4 * r + 2] = v.z; hd[4 * r + 3] = v.w;
        }
        ss += v.x * v.x + v.y * v.y + v.z * v.z + v.w * v.w;
      }
#pragma unroll
      for (int r = 0; r < 2; ++r) {
        float4 v = *(const float4*)&xc[e0 + 64 + 4 * r];
        tl[4 * r + 0] = v.x; tl[4 * r + 1] = v.y;
        tl[4 * r + 2] = v.z; tl[4 * r + 3] = v.w;
      }
    } else {
#pragma unroll
      for (int j = 0; j < 72; ++j) {  // fully unrolled -> compile-time indices
        int g = e0 + j;
        float v = xc[g < 4096 ? g : 4095];
        if (j < 8) hd[j] = v;
        if (j >= 64) tl[j - 64] = v;
        if (j < 64) ss += v * v;
      }
    }
    float ov[8];
#pragma unroll
    for (int i = 0; i < 8; ++i) {
      float iw = 0.0625f / fmaxf(sqrtf(fmaxf(ss, 0.f)), 1e-8f);
      ov[i] = (e0 + i < 4033) ? iw : 0.f;  // kill padded windows
      ss += tl[i] * tl[i] - hd[i] * hd[i];
    }
    *(float4*)&invwb[c * IWS + wb] = make_float4(ov[0], ov[1], ov[2], ov[3]);
    *(float4*)&invwb[c * IWS + wb + 4] = make_float4(ov[4], ov[5], ov[6], ov[7]);
  }

  __syncthreads();

  // ---- phase B: 8 channels per wave, barrier-free ----
  f32x4 acc[4][4];
#pragma unroll
  for (int mt = 0; mt < 4; ++mt)
#pragma unroll
    for (int nt = 0; nt < 4; ++nt) acc[mt][nt] = (f32x4){0.f, 0.f, 0.f, 0.f};

  const int m = lane & 15;
  const int h = lane >> 4;
  const int wgrp = wid >> 1;  // 0..3: 64 windows each
  const int cgrp = wid & 1;   // 0..1: channels 0-7 / 8-15
  const u32* xbase = xs + (m & 3) * SSTRIDE;          // shift copy = m&3
  const int joff = 32 * wgrp + 2 * (m >> 2) + 4 * h;  // even -> 8B-aligned b64 reads
  const u16* shb = shn2 + lane * 8;                   // + c*4096 + (nt*2+ks)*512
  const int iwbase = 64 * wgrp + 4 * h;               // + c*IWS + 16*mt

  for (int i = 0; i < 8; ++i) {
    const int c = cgrp * 8 + i;
    const u32* xc = xbase + c * CSTRIDE;
    bf16x8 af[6];  // f = mt + 2*ks  (shared across mt/ks)
#pragma unroll
    for (int f = 0; f < 6; ++f) {
      const u32* p = xc + joff + 8 * f;
      uint2 lo = *(const uint2*)p;
      uint2 hi = *(const uint2*)(p + 2);
      af[f] = __builtin_bit_cast(bf16x8, make_uint4(lo.x, lo.y, hi.x, hi.y));
    }
    f32x4 iwq[4];
#pragma unroll
    for (int mt = 0; mt < 4; ++mt)
      iwq[mt] = *(const f32x4*)&invwb[c * IWS + iwbase + 16 * mt];
    const u16* sc = shb + c * 4096;
#pragma unroll
    for (int nt = 0; nt < 4; ++nt) {  // b live range = 8 regs
      bf16x8 b0 = __builtin_bit_cast(bf16x8, *(const uint4*)(sc + (nt * 2 + 0) * 512));
      bf16x8 b1 = __builtin_bit_cast(bf16x8, *(const uint4*)(sc + (nt * 2 + 1) * 512));
#pragma unroll
      for (int mt = 0; mt < 4; ++mt) {
        f32x4 d = {0.f, 0.f, 0.f, 0.f};
        d = __builtin_amdgcn_mfma_f32_16x16x32_bf16(af[mt],     b0, d, 0, 0, 0);
        d = __builtin_amdgcn_mfma_f32_16x16x32_bf16(af[mt + 2], b1, d, 0, 0, 0);
        acc[mt][nt] += iwq[mt] * d;
      }
    }
  }

  // ---- cross-cgrp reduction: cgrp1 partials added into cgrp0's acc, per mt-slice ----
#pragma unroll
  for (int mt = 0; mt < 4; ++mt) {
    if (cgrp) {
#pragma unroll
      for (int nt = 0; nt < 4; ++nt)
        *(f32x4*)&red2[wgrp][nt][lane][0] = acc[mt][nt];
    }
    __syncthreads();
    if (!cgrp) {
#pragma unroll
      for (int nt = 0; nt < 4; ++nt)
        acc[mt][nt] += *(const f32x4*)&red2[wgrp][nt][lane][0];
    }
    __syncthreads();
  }

  // ---- epilogue (cgrp0 waves): relu+max over w, shfl over h, redbuf, 1 atomic/out ----
  if (!cgrp) {
#pragma unroll
    for (int nt = 0; nt < 4; ++nt) {
      float v = 0.f;  // relu floor
#pragma unroll
      for (int mt = 0; mt < 4; ++mt)
        v = fmaxf(v, fmaxf(fmaxf(acc[mt][nt].x, acc[mt][nt].y),
                           fmaxf(acc[mt][nt].z, acc[mt][nt].w)));
      v = fmaxf(v, __shfl_xor(v, 16, 64));
      v = fmaxf(v, __shfl_xor(v, 32, 64));
      if (lane < 16) atomicMax(&redbuf[nt * 16 + lane], __float_as_int(v));
    }
  }
  __syncthreads();
  if (tid < 64) atomicMax((int*)&out[b * 64 + tid], redbuf[tid]);
}

extern "C" void kernel_launch(void* const* d_in, const int* in_sizes, int n_in,
                              void* d_out, int out_size, void* d_ws, size_t ws_size,
                              hipStream_t stream) {
  const float* x = (const float*)d_in[0];
  const float* sh = (const float*)d_in[1];
  float* out = (float*)d_out;
  u16* shn2 = (u16*)d_ws;  // 16*64*64 bf16 = 131072 B, fragment-ordered

  prep_kernel<<<dim3(64), dim3(256), 0, stream>>>(sh, shn2, out);
  main_kernel<<<dim3(16, 32), dim3(512), 0, stream>>>(x, shn2, out);
}

// Round 14
// 36.936 us; speedup vs baseline: 3.1115x; 3.1115x over previous
//
#include <hip/hip_runtime.h>

typedef unsigned int u32;
typedef unsigned short u16;
typedef __bf16 bf16x8 __attribute__((ext_vector_type(8)));
typedef float f32x4 __attribute__((ext_vector_type(4)));

static __device__ __forceinline__ u16 f2bf(float f) {
  u32 u = __float_as_uint(f);
  return (u16)((u + 0x7fffu + ((u >> 16) & 1u)) >> 16);  // RTNE
}
static __device__ __forceinline__ float b2f(u16 v) {
  return __uint_as_float(((u32)v) << 16);
}
static __device__ __forceinline__ u32 pk2(u16 lo, u16 hi) {
  return (u32)lo | ((u32)hi << 16);
}

// ---- prep: zero out; L2-normalize shapelets over s; emit bf16 in FRAGMENT order ----
// chunk = c*8 + (k>>4)*2 + (s>>5) (512 u16); lane L=(m+16h) holds elems [L*8,L*8+8)
// = shn[k=(k>>4)*16+m][s=(s>>5)*32+8h .. +7].
// grid 256: one row (c*64+k) per wave, 4 rows per block.
__global__ __launch_bounds__(256) void prep_kernel(const float* __restrict__ sh,
                                                   u16* __restrict__ shn2,
                                                   float* __restrict__ out) {
  if (blockIdx.x == 0) {  // zero the 32*64 output (atomicMax target)
    float4 z = {0.f, 0.f, 0.f, 0.f};
    *(float4*)&out[threadIdx.x * 8] = z;
    *(float4*)&out[threadIdx.x * 8 + 4] = z;
  }
  const int s = threadIdx.x & 63;
  const int wv = threadIdx.x >> 6;
  const int row = blockIdx.x * 4 + wv;  // = c*64 + k
  float v = sh[row * 64 + s];
  float ss = v * v;
#pragma unroll
  for (int o = 1; o < 64; o <<= 1) ss += __shfl_xor(ss, o, 64);
  float iw = 1.0f / fmaxf(sqrtf(ss), 1e-8f);
  const int c = row >> 6, k = row & 63;
  const int chunk = c * 8 + (k >> 4) * 2 + (s >> 5);
  const int pos = ((k & 15) + (((s & 31) >> 3) << 4)) * 8 + (s & 7);
  shn2[chunk * 512 + pos] = f2bf(v * iw);
}

#define WT 256
#define CSTRIDE 168   // u32 per (copy, channel): 160 data + 8 pad (≡8 mod 32)
#define SSTRIDE 2728  // u32 per shift-copy: 16*168 + 40 pad (≡8 mod 32)

// grid (16, 32): blockIdx.x = w-tile (256 w's), blockIdx.y = b.
// 8 waves = 4 w-groups x 2 k-groups; wave tile = 64 w x 32 k.
// bound (512,2): cap 128 (ledger: alloc ~96-112, no spill, 16 waves/CU).
__global__ __launch_bounds__(512, 2) void main_kernel(const float* __restrict__ x,
                                                      const u16* __restrict__ shn2,
                                                      float* __restrict__ out) {
  __shared__ u32 xs[4 * SSTRIDE];  // 43648 B: bf16 x-slice, 4 shifted pair-packed copies
  __shared__ u16 invwb[16 * WT];   // 8192 B : bf16 inv-window-norms (pre-multiplied 1/C)
  __shared__ int redbuf[64];       // per-block max reduction

  const int tid = threadIdx.x;
  const int lane = tid & 63;
  const int wid = tid >> 6;
  const int w0 = blockIdx.x * WT;
  const int b = blockIdx.y;
  const float* xb = x + (size_t)b * 16 * 4096;

  if (tid < 64) redbuf[tid] = 0;

  // ---- phase A1: stage x-slice as bf16; copy s holds pairs (2j+s, 2j+s+1) ----
  {
    const int q = tid & 31;  // chunk: elems [16q, 16q+20)
    const int c = tid >> 5;
    if (q < 20) {
      const float* xc = xb + c * 4096;
      const int e0 = w0 + 16 * q;
      float xv[20];
      if (e0 + 19 < 4096) {
#pragma unroll
        for (int r = 0; r < 5; ++r) *(float4*)&xv[4 * r] = *(const float4*)&xc[e0 + 4 * r];
      } else {
#pragma unroll
        for (int j = 0; j < 20; ++j) {
          int g = e0 + j;
          xv[j] = xc[g < 4096 ? g : 4095];
        }
      }
      u16 bf[20];
#pragma unroll
      for (int j = 0; j < 20; ++j) bf[j] = f2bf(xv[j]);
#pragma unroll
      for (int s = 0; s < 4; ++s) {
        u32 pk[8];
#pragma unroll
        for (int r = 0; r < 8; ++r) pk[r] = pk2(bf[2 * r + s], bf[2 * r + s + 1]);
        u32* dst = &xs[s * SSTRIDE + c * CSTRIDE + 8 * q];
        *(uint4*)dst = make_uint4(pk[0], pk[1], pk[2], pk[3]);
        *(uint4*)(dst + 4) = make_uint4(pk[4], pk[5], pk[6], pk[7]);
      }
    }
  }

  // ---- phase A2: window inverse norms, streaming (low register pressure) ----
  {
    const int c = tid >> 5;
    const int wb = (tid & 31) * 8;
    const float* xc = xb + c * 4096;
    const int e0 = w0 + wb;
    float hd[8], tl[8], ss = 0.f;
    if (e0 + 71 < 4096) {
#pragma unroll
      for (int r = 0; r < 16; ++r) {
        float4 v = *(const float4*)&xc[e0 + 4 * r];
        if (r < 2) {
          hd[4 * r + 0] = v.x; hd[4 * r + 1] = v.y;
          hd[4 * r + 2] = v.z; hd[4 * r + 3] = v.w;
        }
        ss += v.x * v.x + v.y * v.y + v.z * v.z + v.w * v.w;
      }
#pragma unroll
      for (int r = 0; r < 2; ++r) {
        float4 v = *(const float4*)&xc[e0 + 64 + 4 * r];
        tl[4 * r + 0] = v.x; tl[4 * r + 1] = v.y;
        tl[4 * r + 2] = v.z; tl[4 * r + 3] = v.w;
      }
    } else {
#pragma unroll
      for (int j = 0; j < 72; ++j) {  // fully unrolled -> compile-time indices
        int g = e0 + j;
        float v = xc[g < 4096 ? g : 4095];
        if (j < 8) hd[j] = v;
        if (j >= 64) tl[j - 64] = v;
        if (j < 64) ss += v * v;
      }
    }
    u16 ov[8];
#pragma unroll
    for (int i = 0; i < 8; ++i) {
      float iw = 0.0625f / fmaxf(sqrtf(fmaxf(ss, 0.f)), 1e-8f);
      ov[i] = (e0 + i < 4033) ? f2bf(iw) : (u16)0;  // kill padded windows
      ss += tl[i] * tl[i] - hd[i] * hd[i];
    }
    *(uint4*)&invwb[c * WT + wb] = make_uint4(pk2(ov[0], ov[1]), pk2(ov[2], ov[3]),
                                              pk2(ov[4], ov[5]), pk2(ov[6], ov[7]));
  }

  __syncthreads();  // the ONLY barrier before the epilogue

  // ---- phase B: 16 channels, barrier-free. A from LDS (b64), B from global
  //      with next-channel register prefetch; setprio around the MFMA cluster. ----
  f32x4 acc[4][2];
#pragma unroll
  for (int mt = 0; mt < 4; ++mt)
#pragma unroll
    for (int nt = 0; nt < 2; ++nt) acc[mt][nt] = (f32x4){0.f, 0.f, 0.f, 0.f};

  const int m = lane & 15;
  const int h = lane >> 4;
  const int wgrp = wid >> 1;  // 0..3: 64 windows each
  const int kgrp = wid & 1;   // 0..1: 32 k each
  const u32* xbase = xs + (m & 3) * SSTRIDE;           // shift copy = m&3
  const int joff = 32 * wgrp + 2 * (m >> 2) + 4 * h;   // even -> 8B-aligned b64 reads
  const u16* shb = shn2 + lane * 8 + kgrp * 2 * 1024;  // + c*4096 + (nt*2+ks)*512
  const int iwbase = 64 * wgrp + 4 * h;                // + c*WT + 16*mt

  // prefetch B-fragments for c = 0
  uint4 nb0 = *(const uint4*)(shb + 0 * 512);
  uint4 nb1 = *(const uint4*)(shb + 1 * 512);
  uint4 nb2 = *(const uint4*)(shb + 2 * 512);
  uint4 nb3 = *(const uint4*)(shb + 3 * 512);

#pragma unroll 2
  for (int c = 0; c < 16; ++c) {
    // consume this channel's prefetched B-fragments
    bf16x8 b00 = __builtin_bit_cast(bf16x8, nb0);
    bf16x8 b01 = __builtin_bit_cast(bf16x8, nb1);
    bf16x8 b10 = __builtin_bit_cast(bf16x8, nb2);
    bf16x8 b11 = __builtin_bit_cast(bf16x8, nb3);
    if (c < 15) {  // issue next channel's loads early; waited next iteration
      const u16* sn = shb + (c + 1) * 4096;
      nb0 = *(const uint4*)(sn + 0 * 512);
      nb1 = *(const uint4*)(sn + 1 * 512);
      nb2 = *(const uint4*)(sn + 2 * 512);
      nb3 = *(const uint4*)(sn + 3 * 512);
    }
    const u32* xc = xbase + c * CSTRIDE;
    bf16x8 af[6];  // f = mt + 2*ks  (frags 2,3 shared between ks passes)
#pragma unroll
    for (int f = 0; f < 6; ++f) {
      const u32* p = xc + joff + 8 * f;
      uint2 lo = *(const uint2*)p;
      uint2 hi = *(const uint2*)(p + 2);
      af[f] = __builtin_bit_cast(bf16x8, make_uint4(lo.x, lo.y, hi.x, hi.y));
    }
    __builtin_amdgcn_s_setprio(1);
#pragma unroll
    for (int mt = 0; mt < 4; ++mt) {
      ushort4 r4 = *(const ushort4*)&invwb[c * WT + iwbase + 16 * mt];
      f32x4 iw = {b2f(r4.x), b2f(r4.y), b2f(r4.z), b2f(r4.w)};
      f32x4 d0 = {0.f, 0.f, 0.f, 0.f}, d1 = {0.f, 0.f, 0.f, 0.f};
      d0 = __builtin_amdgcn_mfma_f32_16x16x32_bf16(af[mt],     b00, d0, 0, 0, 0);
      d0 = __builtin_amdgcn_mfma_f32_16x16x32_bf16(af[mt + 2], b01, d0, 0, 0, 0);
      d1 = __builtin_amdgcn_mfma_f32_16x16x32_bf16(af[mt],     b10, d1, 0, 0, 0);
      d1 = __builtin_amdgcn_mfma_f32_16x16x32_bf16(af[mt + 2], b11, d1, 0, 0, 0);
      acc[mt][0] += iw * d0;
      acc[mt][1] += iw * d1;
    }
    __builtin_amdgcn_s_setprio(0);
  }

  // ---- epilogue: relu+max over w within wave, LDS-reduce across waves, 1 atomic/out ----
#pragma unroll
  for (int nt = 0; nt < 2; ++nt) {
    float v = 0.f;  // relu floor
#pragma unroll
    for (int mt = 0; mt < 4; ++mt)
      v = fmaxf(v, fmaxf(fmaxf(acc[mt][nt].x, acc[mt][nt].y),
                         fmaxf(acc[mt][nt].z, acc[mt][nt].w)));
    v = fmaxf(v, __shfl_xor(v, 16, 64));
    v = fmaxf(v, __shfl_xor(v, 32, 64));
    if (lane < 16) atomicMax(&redbuf[kgrp * 32 + nt * 16 + lane], __float_as_int(v));
  }
  __syncthreads();
  if (tid < 64) atomicMax((int*)&out[b * 64 + tid], redbuf[tid]);
}

extern "C" void kernel_launch(void* const* d_in, const int* in_sizes, int n_in,
                              void* d_out, int out_size, void* d_ws, size_t ws_size,
                              hipStream_t stream) {
  const float* x = (const float*)d_in[0];
  const float* sh = (const float*)d_in[1];
  float* out = (float*)d_out;
  u16* shn2 = (u16*)d_ws;  // 16*64*64 bf16 = 131072 B, fragment-ordered

  prep_kernel<<<dim3(256), dim3(256), 0, stream>>>(sh, shn2, out);
  main_kernel<<<dim3(16, 32), dim3(512), 0, stream>>>(x, shn2, out);
}